// Round 5
// baseline (133.902 us; speedup 1.0000x reference)
//
#include <hip/hip_runtime.h>
#include <hip/hip_bf16.h>

#define BIGF 1e30f

constexpr int T   = 128;    // trajectory points
constexpr int NB  = 16;     // roads
constexpr int NP  = 256;    // points per road
constexpr int NS  = NP - 1; // segments per branch (255)
constexpr int NB2 = 2 * NB; // fw + bw branches (32)

struct Smem {
  float Px[NP], Py[NP], Pz[NP];   // branch points (reversed in LDS for bw blocks)
  float sl[NS];                   // segment lengths (0 if invalid)
  float t0[NS];                   // p0 projection parameter per segment
  float cum[NP];                  // cumulative arc length, cum[0]=0
  float qx[T], qy[T], qz[T];      // trajectory
  float tcum[T];                  // trajectory cumulative length
  unsigned char pmask[NP];        // point mask
  unsigned long long wmask[4];    // per-wave segment-valid ballot
  float wsumA[4], wsumB[4];       // scan wave totals
  float argf[4]; int argi[4];     // argmin / dist-reduce scratch
  float entry_s, total_s;
  int   max_valid_j, anyseg;
  int   is_last;
  int   sel_b, sel_has;
};

// ---- mask dtype sniffing (uniform scalar loads, broadcast — effectively free):
// lengths >= 2 guarantees mask[0,0,0]=mask[0,0,1]=true ----
__device__ __forceinline__ int sniff_mask_kind(const void* rm) {
  const unsigned char* u = (const unsigned char*)rm;
  unsigned char b0 = u[0], b1 = u[1], b4 = u[4];
  if (b0 == 1 && b1 == 1) return 0;                  // u8 / bool
  if (b0 == 1 && b1 == 0) return (b4 == 1) ? 1 : 2;  // i32 : i64
  if (b0 == 0) return 4;                             // f32
  return 3;                                          // bf16
}

__device__ __forceinline__ bool read_mask(const void* rm, int kind, int idx) {
  switch (kind) {
    case 0:  return ((const unsigned char*)rm)[idx] != 0;
    case 1:  return ((const int*)rm)[idx] != 0;
    case 2:  return ((const long long*)rm)[idx] != 0;
    case 3:  { unsigned short v = ((const unsigned short*)rm)[idx];
               return (unsigned short)(v << 1) != 0; }
    default: return ((const float*)rm)[idx] != 0.0f;
  }
}

// One block per (n, branch2). Computes cost + projected points; the last block
// to finish for each n (device-scope semaphore) performs selection + output.
__global__ __launch_bounds__(256) void k_fused(const float* __restrict__ traj,
                                               const float* __restrict__ rp,
                                               const void* __restrict__ rm,
                                               unsigned int* cnt,
                                               float* cost_ws, float* proj_ws,
                                               float* out) {
  __shared__ Smem s;
  const int tid  = threadIdx.x;
  const int lane = tid & 63;
  const int w    = tid >> 6;
  const int n    = (int)blockIdx.x >> 5;
  const int b2   = (int)blockIdx.x & 31;
  const int r    = b2 & (NB - 1);
  const int rev  = b2 >> 4;
  const int mkind = sniff_mask_kind(rm);

  // --- stage trajectory + branch points: read forward-order (coalesced),
  //     write reversed into LDS for bw blocks (stride ±1: conflict-free) ---
  if (tid < T) {
    int base = (n * T + tid) * 3;
    s.qx[tid] = traj[base + 0];
    s.qy[tid] = traj[base + 1];
    s.qz[tid] = traj[base + 2];
  }
  {
    int k = rev ? (NP - 1 - tid) : tid;
    int midx  = (n * NB + r) * NP + tid;
    int pbase = midx * 3;
    s.Px[k] = rp[pbase + 0];
    s.Py[k] = rp[pbase + 1];
    s.Pz[k] = rp[pbase + 2];
    s.pmask[k] = read_mask(rm, mkind, midx) ? 1 : 0;
  }
  __syncthreads();                              // B1: staging complete

  // --- per-segment data + p0 projection candidate (registers) ---
  float d2 = BIGF;
  int   idx = tid;
  float slv = 0.0f;
  int   smf = 0;
  if (tid < NS) {
    float ax = s.Px[tid], ay = s.Py[tid], az = s.Pz[tid];
    float svx = s.Px[tid + 1] - ax, svy = s.Py[tid + 1] - ay, svz = s.Pz[tid + 1] - az;
    smf = s.pmask[tid] & s.pmask[tid + 1];
    float svd2 = svx * svx + svy * svy + svz * svz;
    slv = smf ? sqrtf(svd2) : 0.0f;
    s.sl[tid] = slv;
    float px = s.qx[0], py = s.qy[0], pz = s.qz[0];
    float dx = px - ax, dy = py - ay, dz = pz - az;
    float svd = fmaxf(svd2, 1e-12f);
    float t0v = fminf(fmaxf((dx * svx + dy * svy + dz * svz) / svd, 0.0f), 1.0f);
    s.t0[tid] = t0v;
    float qx0 = ax + t0v * svx, qy0 = ay + t0v * svy, qz0 = az + t0v * svz;
    float ex = px - qx0, ey = py - qy0, ez = pz - qz0;
    d2 = smf ? (ex * ex + ey * ey + ez * ez) : BIGF;
  }
  {
    unsigned long long m = __ballot(smf != 0);
    if (lane == 0) s.wmask[w] = m;
  }
  // per-wave argmin (lexicographic (d2, idx) == numpy first-min)
  for (int off = 32; off; off >>= 1) {
    float od = __shfl_xor(d2, off, 64);
    int   oi = __shfl_xor(idx, off, 64);
    if (od < d2 || (od == d2 && oi < idx)) { d2 = od; idx = oi; }
  }
  if (lane == 0) { s.argf[w] = d2; s.argi[w] = idx; }

  // traj segment length (registers)
  float tlv = 0.0f;
  if (tid < T - 1) {
    float dx = s.qx[tid + 1] - s.qx[tid];
    float dy = s.qy[tid + 1] - s.qy[tid];
    float dz = s.qz[tid + 1] - s.qz[tid];
    tlv = sqrtf(dx * dx + dy * dy + dz * dz);
  }

  // --- fused parallel inclusive scan of (slv, tlv) via wave shuffles ---
  float xa = slv, xb = tlv;
  #pragma unroll
  for (int off = 1; off < 64; off <<= 1) {
    float ya = __shfl_up(xa, off, 64);
    float yb = __shfl_up(xb, off, 64);
    if (lane >= off) { xa += ya; xb += yb; }
  }
  if (lane == 63) { s.wsumA[w] = xa; s.wsumB[w] = xb; }
  __syncthreads();                              // B2: wave totals + sl/t0 visible
  {
    float pa = 0.0f, pb = 0.0f;
    if (w > 0) { pa += s.wsumA[0]; pb += s.wsumB[0]; }
    if (w > 1) { pa += s.wsumA[1]; pb += s.wsumB[1]; }
    if (w > 2) { pa += s.wsumA[2]; pb += s.wsumB[2]; }
    xa += pa; xb += pb;
  }
  if (tid < NS)    s.cum[tid + 1]  = xa;
  if (tid < T - 1) s.tcum[tid + 1] = xb;
  if (tid == 255)  { s.cum[0] = 0.0f; s.tcum[0] = 0.0f; s.total_s = xa; }
  __syncthreads();                              // B3: cum/tcum ready

  if (tid == 0) {
    float bd = s.argf[0]; int bi = s.argi[0];
    #pragma unroll
    for (int ww = 1; ww < 4; ++ww)
      if (s.argf[ww] < bd || (s.argf[ww] == bd && s.argi[ww] < bi)) { bd = s.argf[ww]; bi = s.argi[ww]; }
    s.entry_s = s.cum[bi] + s.t0[bi] * s.sl[bi];
    int mj = 0, any = 0;
    #pragma unroll
    for (int ww = 3; ww >= 0; --ww) {
      unsigned long long m = s.wmask[ww];
      if (m) { any = 1; mj = ww * 64 + 63 - __clzll(m); break; }
    }
    s.max_valid_j = mj;
    s.anyseg = any;
  }
  __syncthreads();                              // B4: entry_s/max_valid_j ready

  // --- per-trajectory-point projection + store + distance ---
  float dist = 0.0f;
  if (tid < T) {
    float target = s.entry_s + s.tcum[tid];
    target = fminf(target, s.total_s);
    target = fmaxf(target, 0.0f);
    int lo = 0, hi = NP;                        // j = count(cum <= target) - 1
    while (lo < hi) {
      int mid = (lo + hi) >> 1;
      if (s.cum[mid] <= target) lo = mid + 1; else hi = mid;
    }
    int j = lo - 1;
    if (j < 0) j = 0;
    int mvj = s.max_valid_j;
    if (j > mvj) j = mvj;
    float tl = (target - s.cum[j]) / fmaxf(s.sl[j], 1e-9f);
    tl = fminf(fmaxf(tl, 0.0f), 1.0f);
    float ax = s.Px[j], ay = s.Py[j], az = s.Pz[j];
    float prx = ax + tl * (s.Px[j + 1] - ax);
    float pry = ay + tl * (s.Py[j + 1] - ay);
    float prz = az + tl * (s.Pz[j + 1] - az);
    int ob = ((n * NB2 + b2) * T + tid) * 3;
    proj_ws[ob + 0] = prx;
    proj_ws[ob + 1] = pry;
    proj_ws[ob + 2] = prz;
    float dx = s.qx[tid] - prx, dy = s.qy[tid] - pry, dz = s.qz[tid] - prz;
    dist = sqrtf(dx * dx + dy * dy + dz * dz);
  }
  for (int off = 32; off; off >>= 1) dist += __shfl_xor(dist, off, 64);
  if (lane == 0) s.argf[w] = dist;              // WAR over B4 — safe
  __syncthreads();                              // B5: vmcnt(0) drained -> proj stores at L2

  // --- release: publish cost, flush L2, bump per-n semaphore ---
  if (tid == 0) {
    float c = s.argf[0] + s.argf[1] + s.argf[2] + s.argf[3];
    cost_ws[n * NB2 + b2] = s.anyseg ? c : BIGF;
    __threadfence();                            // device-scope release (L2 writeback)
    unsigned int old = atomicAdd(&cnt[n], 1u);  // device-scope atomic
    s.is_last = (old == NB2 - 1);
  }
  __syncthreads();
  if (!s.is_last) return;                       // whole-block uniform

  // --- last block for this n: acquire, select best branch, write output ---
  __threadfence();                              // device-scope acquire (L2 invalidate)
  if (w == 0) {
    float cc = (lane < NB2) ? cost_ws[n * NB2 + lane] : BIGF;
    int   ii = lane;
    for (int off = 32; off; off >>= 1) {
      float oc = __shfl_xor(cc, off, 64);
      int   oi = __shfl_xor(ii, off, 64);
      if (oc < cc || (oc == cc && oi < ii)) { cc = oc; ii = oi; }
    }
    if (lane == 0) { s.sel_b = ii; s.sel_has = (cc < BIGF) ? 1 : 0; }
  }
  __syncthreads();
  int bi = s.sel_b, has = s.sel_has;
  if (has) {
    const float* src = proj_ws + (size_t)((n * NB2 + bi) * T) * 3;
    float* dst = out + (size_t)(n * T) * 3;
    for (int i = tid; i < T * 3; i += 256) dst[i] = src[i];
  } else {
    const float* src = traj + (size_t)(n * T) * 3;
    float* dst = out + (size_t)(n * T) * 3;
    for (int i = tid; i < T * 3; i += 256) dst[i] = src[i];
  }
}

extern "C" void kernel_launch(void* const* d_in, const int* in_sizes, int n_in,
                              void* d_out, int out_size, void* d_ws, size_t ws_size,
                              hipStream_t stream) {
  const float* traj = (const float*)d_in[0];   // (N,T,3) f32 (proven bit-exact R3)
  const float* rp   = (const float*)d_in[1];   // (N,NB,NP,3) f32
  const void*  rm   = d_in[2];                 // (N,NB,NP) mask, dtype sniffed
  float* out = (float*)d_out;                  // (N,T,3) f32

  int N = in_sizes[0] / (T * 3);

  unsigned int* cnt = (unsigned int*)d_ws;                    // N semaphores
  float* cost_ws = (float*)(cnt + N);                         // N*NB2 floats
  float* proj_ws = cost_ws + (size_t)N * NB2;                 // N*NB2*T*3 floats

  hipMemsetAsync(cnt, 0, (size_t)N * sizeof(unsigned int), stream);
  k_fused<<<dim3(N * NB2), dim3(256), 0, stream>>>(rp ? traj : traj, rp, rm,
                                                   cnt, cost_ws, proj_ws, out);
}

// Round 9
// 68.585 us; speedup vs baseline: 1.9523x; 1.9523x over previous
//
#include <hip/hip_runtime.h>
#include <hip/hip_bf16.h>

#define BIGF 1e30f

constexpr int T   = 128;    // trajectory points
constexpr int NB  = 16;     // roads
constexpr int NP  = 256;    // points per road
constexpr int NS  = NP - 1; // segments per branch (255)
constexpr int NB2 = 2 * NB; // fw + bw branches (32)

struct Smem {
  float Px[NP], Py[NP], Pz[NP];   // branch points (reversed in LDS for bw blocks)
  float sl[NS];                   // segment lengths (0 if invalid)
  float t0[NS];                   // p0 projection parameter per segment
  float cum[NP];                  // cumulative arc length, cum[0]=0
  float qx[T], qy[T], qz[T];      // trajectory
  float tcum[T];                  // trajectory cumulative length
  unsigned char pmask[NP];        // point mask
  unsigned long long wmask[4];    // per-wave segment-valid ballot
  float wsumA[4], wsumB[4];       // scan wave totals
  float argf[4]; int argi[4];     // p0-argmin per-wave results
  float distf[4];                 // distance-sum per-wave results (separate: no WAR)
};

// ---- mask dtype sniffing (uniform scalar loads, broadcast — effectively free):
// lengths >= 2 guarantees mask[0,0,0]=mask[0,0,1]=true ----
__device__ __forceinline__ int sniff_mask_kind(const void* rm) {
  const unsigned char* u = (const unsigned char*)rm;
  unsigned char b0 = u[0], b1 = u[1], b4 = u[4];
  if (b0 == 1 && b1 == 1) return 0;                  // u8 / bool
  if (b0 == 1 && b1 == 0) return (b4 == 1) ? 1 : 2;  // i32 : i64
  if (b0 == 0) return 4;                             // f32
  return 3;                                          // bf16
}

__device__ __forceinline__ bool read_mask(const void* rm, int kind, int idx) {
  switch (kind) {
    case 0:  return ((const unsigned char*)rm)[idx] != 0;
    case 1:  return ((const int*)rm)[idx] != 0;
    case 2:  return ((const long long*)rm)[idx] != 0;
    case 3:  { unsigned short v = ((const unsigned short*)rm)[idx];
               return (unsigned short)(v << 1) != 0; }
    default: return ((const float*)rm)[idx] != 0.0f;
  }
}

// k1: one block per (n, branch2). Cost + projected points.
// NOTE (R5 lesson): do NOT fuse selection via per-block __threadfence/semaphore —
// the 2048 device-scope release fences (buffer_wbl2) cost ~55 µs; the stream-ordered
// kernel boundary to k2 is the free release/acquire.
__global__ __launch_bounds__(256) void k1_costs(const float* __restrict__ traj,
                                                const float* __restrict__ rp,
                                                const void* __restrict__ rm,
                                                float* cost_ws, float* proj_ws) {
  __shared__ Smem s;
  const int tid  = threadIdx.x;
  const int lane = tid & 63;
  const int w    = tid >> 6;
  const int n    = (int)blockIdx.x >> 5;
  const int b2   = (int)blockIdx.x & 31;
  const int r    = b2 & (NB - 1);
  const int rev  = b2 >> 4;
  const int mkind = sniff_mask_kind(rm);

  // --- stage: read forward-order (coalesced), write reversed into LDS for bw ---
  if (tid < T) {
    int base = (n * T + tid) * 3;
    s.qx[tid] = traj[base + 0];
    s.qy[tid] = traj[base + 1];
    s.qz[tid] = traj[base + 2];
  }
  {
    int k = rev ? (NP - 1 - tid) : tid;
    int midx  = (n * NB + r) * NP + tid;
    int pbase = midx * 3;
    s.Px[k] = rp[pbase + 0];
    s.Py[k] = rp[pbase + 1];
    s.Pz[k] = rp[pbase + 2];
    s.pmask[k] = read_mask(rm, mkind, midx) ? 1 : 0;
  }
  __syncthreads();                              // B1: staging complete

  // --- per-segment data + p0 projection candidate (registers) ---
  float d2 = BIGF;
  int   idx = tid;
  float slv = 0.0f;
  int   smf = 0;
  if (tid < NS) {
    float ax = s.Px[tid], ay = s.Py[tid], az = s.Pz[tid];
    float svx = s.Px[tid + 1] - ax, svy = s.Py[tid + 1] - ay, svz = s.Pz[tid + 1] - az;
    smf = s.pmask[tid] & s.pmask[tid + 1];
    float svd2 = svx * svx + svy * svy + svz * svz;
    slv = smf ? sqrtf(svd2) : 0.0f;
    s.sl[tid] = slv;
    float px = s.qx[0], py = s.qy[0], pz = s.qz[0];
    float dx = px - ax, dy = py - ay, dz = pz - az;
    float svd = fmaxf(svd2, 1e-12f);
    float t0v = fminf(fmaxf((dx * svx + dy * svy + dz * svz) / svd, 0.0f), 1.0f);
    s.t0[tid] = t0v;
    float qx0 = ax + t0v * svx, qy0 = ay + t0v * svy, qz0 = az + t0v * svz;
    float ex = px - qx0, ey = py - qy0, ez = pz - qz0;
    d2 = smf ? (ex * ex + ey * ey + ez * ez) : BIGF;
  }
  {
    unsigned long long m = __ballot(smf != 0);
    if (lane == 0) s.wmask[w] = m;
  }
  // per-wave argmin (lexicographic (d2, idx) == numpy first-min)
  for (int off = 32; off; off >>= 1) {
    float od = __shfl_xor(d2, off, 64);
    int   oi = __shfl_xor(idx, off, 64);
    if (od < d2 || (od == d2 && oi < idx)) { d2 = od; idx = oi; }
  }
  if (lane == 0) { s.argf[w] = d2; s.argi[w] = idx; }

  // traj segment length (registers)
  float tlv = 0.0f;
  if (tid < T - 1) {
    float dx = s.qx[tid + 1] - s.qx[tid];
    float dy = s.qy[tid + 1] - s.qy[tid];
    float dz = s.qz[tid + 1] - s.qz[tid];
    tlv = sqrtf(dx * dx + dy * dy + dz * dz);
  }

  // --- fused parallel inclusive scan of (slv, tlv) via wave shuffles ---
  float xa = slv, xb = tlv;
  #pragma unroll
  for (int off = 1; off < 64; off <<= 1) {
    float ya = __shfl_up(xa, off, 64);
    float yb = __shfl_up(xb, off, 64);
    if (lane >= off) { xa += ya; xb += yb; }
  }
  if (lane == 63) { s.wsumA[w] = xa; s.wsumB[w] = xb; }
  __syncthreads();                              // B2: wave totals + argf/wmask/sl/t0 visible
  {
    float pa = 0.0f, pb = 0.0f;
    if (w > 0) { pa += s.wsumA[0]; pb += s.wsumB[0]; }
    if (w > 1) { pa += s.wsumA[1]; pb += s.wsumB[1]; }
    if (w > 2) { pa += s.wsumA[2]; pb += s.wsumB[2]; }
    xa += pa; xb += pb;
  }
  float total_s = s.wsumA[0] + s.wsumA[1] + s.wsumA[2] + s.wsumA[3];
  if (tid < NS)    s.cum[tid + 1]  = xa;
  if (tid < T - 1) s.tcum[tid + 1] = xb;
  if (tid == 255)  { s.cum[0] = 0.0f; s.tcum[0] = 0.0f; }
  __syncthreads();                              // B3: cum/tcum ready

  // --- every thread redundantly computes block argmin + entry_s + max_valid_j
  //     (4 compares + broadcast LDS reads; removes the old tid0+barrier phase) ---
  float bd = s.argf[0]; int bi = s.argi[0];
  #pragma unroll
  for (int ww = 1; ww < 4; ++ww)
    if (s.argf[ww] < bd || (s.argf[ww] == bd && s.argi[ww] < bi)) { bd = s.argf[ww]; bi = s.argi[ww]; }
  float entry_s = s.cum[bi] + s.t0[bi] * s.sl[bi];
  int mvj = 0, anyseg = 0;
  #pragma unroll
  for (int ww = 3; ww >= 0; --ww) {
    unsigned long long m = s.wmask[ww];
    if (m) { anyseg = 1; mvj = ww * 64 + 63 - __clzll(m); break; }
  }

  // --- per-trajectory-point projection + store + distance ---
  float dist = 0.0f;
  if (tid < T) {
    float target = entry_s + s.tcum[tid];
    target = fminf(target, total_s);
    target = fmaxf(target, 0.0f);
    int lo = 0, hi = NP;                        // j = count(cum <= target) - 1
    while (lo < hi) {
      int mid = (lo + hi) >> 1;
      if (s.cum[mid] <= target) lo = mid + 1; else hi = mid;
    }
    int j = lo - 1;
    if (j < 0) j = 0;
    if (j > mvj) j = mvj;
    float tl = (target - s.cum[j]) / fmaxf(s.sl[j], 1e-9f);
    tl = fminf(fmaxf(tl, 0.0f), 1.0f);
    float ax = s.Px[j], ay = s.Py[j], az = s.Pz[j];
    float prx = ax + tl * (s.Px[j + 1] - ax);
    float pry = ay + tl * (s.Py[j + 1] - ay);
    float prz = az + tl * (s.Pz[j + 1] - az);
    int ob = ((n * NB2 + b2) * T + tid) * 3;
    proj_ws[ob + 0] = prx;
    proj_ws[ob + 1] = pry;
    proj_ws[ob + 2] = prz;
    float dx = s.qx[tid] - prx, dy = s.qy[tid] - pry, dz = s.qz[tid] - prz;
    dist = sqrtf(dx * dx + dy * dy + dz * dz);
  }
  for (int off = 32; off; off >>= 1) dist += __shfl_xor(dist, off, 64);
  if (lane == 0) s.distf[w] = dist;
  __syncthreads();                              // B4(final): dist partials ready
  if (tid == 0) {
    float c = s.distf[0] + s.distf[1] + s.distf[2] + s.distf[3];
    cost_ws[n * NB2 + b2] = anyseg ? c : BIGF;
  }
}

// k2: one block per n — argmin over 32 costs, gather winning projection.
__global__ __launch_bounds__(128) void k2_select(const float* __restrict__ traj,
                                                 const float* __restrict__ cost_ws,
                                                 const float* __restrict__ proj_ws,
                                                 float* __restrict__ out) {
  __shared__ int sb[2];
  const int n = (int)blockIdx.x;
  const int tid = threadIdx.x;
  if (tid < 64) {
    float cc = (tid < NB2) ? cost_ws[n * NB2 + tid] : BIGF;
    int   ii = tid;
    for (int off = 32; off; off >>= 1) {
      float oc = __shfl_xor(cc, off, 64);
      int   oi = __shfl_xor(ii, off, 64);
      if (oc < cc || (oc == cc && oi < ii)) { cc = oc; ii = oi; }  // numpy first-min
    }
    if (tid == 0) { sb[0] = ii; sb[1] = (cc < BIGF) ? 1 : 0; }
  }
  __syncthreads();
  int bi = sb[0], has = sb[1];
  int ob = (n * T + tid) * 3;
  if (has) {
    int ib = ((n * NB2 + bi) * T + tid) * 3;
    out[ob + 0] = proj_ws[ib + 0];
    out[ob + 1] = proj_ws[ib + 1];
    out[ob + 2] = proj_ws[ib + 2];
  } else {
    out[ob + 0] = traj[ob + 0];
    out[ob + 1] = traj[ob + 1];
    out[ob + 2] = traj[ob + 2];
  }
}

extern "C" void kernel_launch(void* const* d_in, const int* in_sizes, int n_in,
                              void* d_out, int out_size, void* d_ws, size_t ws_size,
                              hipStream_t stream) {
  const float* traj = (const float*)d_in[0];   // (N,T,3) f32 (proven bit-exact R3)
  const float* rp   = (const float*)d_in[1];   // (N,NB,NP,3) f32
  const void*  rm   = d_in[2];                 // (N,NB,NP) mask, dtype sniffed
  float* out = (float*)d_out;                  // (N,T,3) f32

  int N = in_sizes[0] / (T * 3);

  float* cost_ws = (float*)d_ws;                 // N*NB2 floats
  float* proj_ws = cost_ws + (size_t)N * NB2;    // N*NB2*T*3 floats (~3 MB)

  k1_costs<<<dim3(N * NB2), dim3(256), 0, stream>>>(traj, rp, rm, cost_ws, proj_ws);
  k2_select<<<dim3(N), dim3(128), 0, stream>>>(traj, cost_ws, proj_ws, out);
}